// Round 7
// baseline (69.275 us; speedup 1.0000x reference)
//
#include <hip/hip_runtime.h>

// y = relu(x @ W1 + b1) @ W2 + b2  via bf16 MFMA (fp32 accumulate).
// x: [B, 64] f32, W1: [64, 32], b1: [32], W2: [32, 10], b2: [10], y: [B, 10] f32.
//
// Round 7: persistent grid with CONTIGUOUS per-wave spans.
//   R6 (persistent, strided tiles) regressed vs R5: each wave's read stream
//   fell to 4-KB runs strided 12.5 MB -> DRAM row/channel locality loss.
//   This round keeps the tail-free persistent shape (768 blocks = 3/CU,
//   LDS-bound) but assigns wave gw the contiguous tile range
//   [gw*T/GW, (gw+1)*T/GW)  (T=65536 tiles, GW=3072 waves -> n = 21|22),
//   i.e. ~86 KB sequential reads + contiguous writes per wave.
//
//   Pipeline (identical to R5/R6): depth-2 prefetch, 3 LDS buffers,
//   per-iteration VMEM order L_{i+2} w_i S_i with counted waits
//   (loads 4 ops, stores 4 ops, FIFO vmcnt):
//     i==0 -> vmcnt(8); i==1 -> vmcnt(12); 2<=i<n-2 -> vmcnt(16);
//     i==n-2 -> vmcnt(12); i==n-1 -> vmcnt(8).   (valid n>=4; here n>=21)
//   Miscount -> stale frags -> absmax explodes (fail-loud).
//
//   Staging swizzle (both-sides-or-neither): LDS dest LINEAR; global source
//   chunk permuted (chunk m' of row r holds global chunk m'^(r&7)); ds_read
//   applies the same XOR -> 2-way banks (free).
//   A-frag: lane (g,c): row c, k=8g+i. C/D: col=lane&15, row=4*(lane>>4)+reg.
//   h bounce rows PACKED (dword at 4c = (h[c],h[c+16])); W2 frag uses the
//   same k-permutation so the MFMA k-reduction is unchanged.

#define N_IN  64
#define N_MID 32
#define N_OUT 10

#define WAVES_PER_BLOCK 4
#define GRID_BLOCKS     768
#define ROWS_PER_TILE   16
#define NBUF            3
#define H_STRIDE        80        // bytes per h-row in LDS (64 data + 16 pad)
#define XTILE_BYTES     4096      // 16 rows * 256 B
#define ROW_BYTES       256

typedef short bf16x8 __attribute__((ext_vector_type(8)));
typedef float f32x4  __attribute__((ext_vector_type(4)));

typedef __attribute__((address_space(3))) unsigned char       lds_u8_as;
typedef const __attribute__((address_space(1))) unsigned char glb_u8_as;

static __device__ __forceinline__ short f2bf(float f) {
    __bf16 h = (__bf16)f;
    return __builtin_bit_cast(short, h);
}

static __device__ __forceinline__ unsigned pk2bf(float lo, float hi) {
    unsigned l = (unsigned short)__builtin_bit_cast(unsigned short, (__bf16)lo);
    unsigned h = (unsigned short)__builtin_bit_cast(unsigned short, (__bf16)hi);
    return (h << 16) | l;
}

__global__ __launch_bounds__(256)
void livenet_mfma(const float* __restrict__ x,
                  const float* __restrict__ W1,
                  const float* __restrict__ b1,
                  const float* __restrict__ W2,
                  const float* __restrict__ b2,
                  float* __restrict__ out,
                  int batch) {
    __shared__ __align__(16) unsigned char xstage_all[WAVES_PER_BLOCK][NBUF * XTILE_BYTES];
    __shared__ __align__(16) unsigned char h_lds_all[WAVES_PER_BLOCK][ROWS_PER_TILE * H_STRIDE];

    const int lane = threadIdx.x & 63;
    const int wave = threadIdx.x >> 6;
    const int g    = lane >> 4;   // 0..3 : k-group
    const int c    = lane & 15;   // 0..15: row (A) / col (B,C)

    unsigned char* xstage = xstage_all[wave];
    unsigned char* h_lds  = h_lds_all[wave];

    // ---- weight fragments, once per wave ----
    bf16x8 w1f[2][2];  // [n-tile][k-half]
    #pragma unroll
    for (int n = 0; n < 2; ++n)
        #pragma unroll
        for (int p = 0; p < 2; ++p)
            #pragma unroll
            for (int i = 0; i < 8; ++i) {
                int k = p * 32 + 8 * g + i;
                w1f[n][p][i] = f2bf(W1[k * N_MID + n * 16 + c]);
            }

    // W2 fragment in the PACKED-h k-order: position p holds col (p&1)*16+(p>>1).
    bf16x8 w2f;
    #pragma unroll
    for (int i = 0; i < 8; ++i) {
        int kpos = 8 * g + i;
        int col  = (kpos & 1) * 16 + (kpos >> 1);
        w2f[i] = (c < N_OUT) ? f2bf(W2[col * N_OUT + c]) : (short)0;
    }

    const float b1v0 = b1[c];
    const float b1v1 = b1[16 + c];
    const float b2v  = (c < N_OUT) ? b2[c] : 0.0f;

    // ---- per-lane staging source offsets (swizzled global permutation) ----
    const int r_lo    = lane >> 4;
    const int mprime  = lane & 15;
    unsigned srcoff[4];
    #pragma unroll
    for (int j = 0; j < 4; ++j) {
        int r = 4 * j + r_lo;
        srcoff[j] = (unsigned)(r * ROW_BYTES + 16 * (mprime ^ (r & 7)));
    }

    // ---- fragment read offsets (swizzled): row c, chunks {2g,2g+1,8+2g,9+2g} ----
    const int cw = c & 7;
    const unsigned rd_a0lo = (unsigned)(c * ROW_BYTES + 16 * ((2 * g)     ^ cw));
    const unsigned rd_a0hi = (unsigned)(c * ROW_BYTES + 16 * ((2 * g + 1) ^ cw));
    const unsigned rd_a1lo = (unsigned)(c * ROW_BYTES + 16 * ((8 + 2 * g) ^ cw));
    const unsigned rd_a1hi = (unsigned)(c * ROW_BYTES + 16 * ((9 + 2 * g) ^ cw));

    // ---- contiguous per-wave job span: tiles [t0, t1) ----
    const int GW = GRID_BLOCKS * WAVES_PER_BLOCK;               // 3072
    const int gw = blockIdx.x * WAVES_PER_BLOCK + wave;         // 0..3071
    const long long T  = batch / ROWS_PER_TILE;                 // 65536
    const long long t0 = ((long long)gw * T) / GW;
    const long long t1 = ((long long)(gw + 1) * T) / GW;
    const int n = (int)(t1 - t0);                               // 21 | 22

    if (n <= 0) return;

    const unsigned char* xg = (const unsigned char*)x + (size_t)t0 * XTILE_BYTES;

    // ---- prologue: stage tile 0 -> buf0, tile 1 -> buf1 ----
    {
        #pragma unroll
        for (int j = 0; j < 4; ++j) {
            __builtin_amdgcn_global_load_lds(
                (glb_u8_as*)(xg + srcoff[j]),
                (lds_u8_as*)(xstage + 0 * XTILE_BYTES + j * 1024), 16, 0, 0);
        }
        if (n > 1) {
            #pragma unroll
            for (int j = 0; j < 4; ++j) {
                __builtin_amdgcn_global_load_lds(
                    (glb_u8_as*)(xg + XTILE_BYTES + srcoff[j]),
                    (lds_u8_as*)(xstage + 1 * XTILE_BYTES + j * 1024), 16, 0, 0);
            }
        }
    }

    size_t off_s = 2 * (size_t)XTILE_BYTES;          // byte offset of tile i+2
    unsigned curb = 0;                               // LDS buf of tile i
    unsigned stgb = 2 * XTILE_BYTES;                 // LDS buf of tile i+2
    size_t   rb   = (size_t)t0 * ROWS_PER_TILE;      // output row base

    for (int i = 0; i < n; ++i) {
        // ---- issue stage of tile i+2 (before the wait) ----
        if (i + 2 < n) {
            const unsigned char* src = xg + off_s;
            unsigned char* nbuf = xstage + stgb;
            #pragma unroll
            for (int j = 0; j < 4; ++j) {
                __builtin_amdgcn_global_load_lds(
                    (glb_u8_as*)(src + srcoff[j]),
                    (lds_u8_as*)(nbuf + j * 1024), 16, 0, 0);
            }
        }

        // ---- counted wait: guarantee tile i's staging complete (n>=4) ----
        if (i == 0) {
            __asm__ volatile("s_waitcnt vmcnt(8)" ::: "memory");
        } else if (i == 1) {
            __asm__ volatile("s_waitcnt vmcnt(12)" ::: "memory");
        } else if (i == n - 1) {
            __asm__ volatile("s_waitcnt vmcnt(8)" ::: "memory");
        } else if (i == n - 2) {
            __asm__ volatile("s_waitcnt vmcnt(12)" ::: "memory");
        } else {
            __asm__ volatile("s_waitcnt vmcnt(16)" ::: "memory");
        }
        __builtin_amdgcn_sched_barrier(0);

        const unsigned char* xbuf = xstage + curb;

        // ---- fragment reads from staged tile (swizzled, balanced banks) ----
        const float4 f0 = *(const float4*)(xbuf + rd_a0lo);
        const float4 f1 = *(const float4*)(xbuf + rd_a0hi);
        const float4 f2 = *(const float4*)(xbuf + rd_a1lo);
        const float4 f3 = *(const float4*)(xbuf + rd_a1hi);

        // ---- cvt + layer 1 ----
        bf16x8 a0, a1;
        a0[0] = f2bf(f0.x); a0[1] = f2bf(f0.y); a0[2] = f2bf(f0.z); a0[3] = f2bf(f0.w);
        a0[4] = f2bf(f1.x); a0[5] = f2bf(f1.y); a0[6] = f2bf(f1.z); a0[7] = f2bf(f1.w);
        a1[0] = f2bf(f2.x); a1[1] = f2bf(f2.y); a1[2] = f2bf(f2.z); a1[3] = f2bf(f2.w);
        a1[4] = f2bf(f3.x); a1[5] = f2bf(f3.y); a1[6] = f2bf(f3.z); a1[7] = f2bf(f3.w);

        f32x4 acc0 = {b1v0, b1v0, b1v0, b1v0};
        f32x4 acc1 = {b1v1, b1v1, b1v1, b1v1};
        acc0 = __builtin_amdgcn_mfma_f32_16x16x32_bf16(a0, w1f[0][0], acc0, 0, 0, 0);
        acc0 = __builtin_amdgcn_mfma_f32_16x16x32_bf16(a1, w1f[0][1], acc0, 0, 0, 0);
        acc1 = __builtin_amdgcn_mfma_f32_16x16x32_bf16(a0, w1f[1][0], acc1, 0, 0, 0);
        acc1 = __builtin_amdgcn_mfma_f32_16x16x32_bf16(a1, w1f[1][1], acc1, 0, 0, 0);

        // ---- relu + packed transpose write: dword = (h[c], h[c+16]) ----
        #pragma unroll
        for (int r = 0; r < 4; ++r) {
            const int rowr = 4 * g + r;
            *(unsigned*)(h_lds + rowr * H_STRIDE + 4 * c) =
                pk2bf(fmaxf(acc0[r], 0.0f), fmaxf(acc1[r], 0.0f));
        }
        __asm__ volatile("" ::: "memory");

        // ---- layer 2 ----
        const bf16x8 hfrag = *(const bf16x8*)(h_lds + c * H_STRIDE + 16 * g);
        f32x4 acc2 = {b2v, b2v, b2v, b2v};
        acc2 = __builtin_amdgcn_mfma_f32_16x16x32_bf16(hfrag, w2f, acc2, 0, 0, 0);

        __asm__ volatile("" ::: "memory");

        // ---- store: exactly 4 VMEM ops per iteration (exec-masked) ----
        if (c < N_OUT) {
            float* op = out + (rb + 4 * g) * N_OUT + c;
            op[0 * N_OUT] = acc2[0];
            op[1 * N_OUT] = acc2[1];
            op[2 * N_OUT] = acc2[2];
            op[3 * N_OUT] = acc2[3];
        }

        // ---- advance job pointers (sequential tiles) ----
        off_s += XTILE_BYTES;
        rb    += ROWS_PER_TILE;
        curb += XTILE_BYTES; if (curb == NBUF * XTILE_BYTES) curb = 0;
        stgb += XTILE_BYTES; if (stgb == NBUF * XTILE_BYTES) stgb = 0;
    }
}

extern "C" void kernel_launch(void* const* d_in, const int* in_sizes, int n_in,
                              void* d_out, int out_size, void* d_ws, size_t ws_size,
                              hipStream_t stream) {
    const float* x  = (const float*)d_in[0];
    const float* W1 = (const float*)d_in[1];
    const float* b1 = (const float*)d_in[2];
    const float* W2 = (const float*)d_in[3];
    const float* b2 = (const float*)d_in[4];
    float* out = (float*)d_out;

    int batch = in_sizes[0] / N_IN;   // 1048576 (divisible by 16)
    livenet_mfma<<<GRID_BLOCKS, 256, 0, stream>>>(x, W1, b1, W2, b2, out, batch);
}

// Round 8
// 59.739 us; speedup vs baseline: 1.1596x; 1.1596x over previous
//
#include <hip/hip_runtime.h>

// y = relu(x @ W1 + b1) @ W2 + b2  via bf16 MFMA (fp32 accumulate).
// x: [B, 64] f32, W1: [64, 32], b1: [32], W2: [32, 10], b2: [10], y: [B, 10] f32.
//
// Round 8: R5 champion (dispatched grid, depth-2 LDS pipeline) + NONTEMPORAL
// cache policy on both single-pass streams:
//   - x staging loads: global_load_lds aux = 2 (NT bit, gfx9xx CPol) ->
//     no-allocate / last-use in L2 + Infinity Cache (268 MB read once).
//   - y stores: __builtin_nontemporal_store (42 MB written once, never read).
//   Hints are coherence-neutral: values identical, worst case perf-flat.
//
// Pipeline (= R5): 8 tiles/wave, depth-2 prefetch into 3 LDS buffers,
// per-iteration VMEM order L_{t+2} w_t S_t with counted compile-time waits
// (loads 4 ops, stores 4 ops, FIFO vmcnt):
//   t==0 -> vmcnt(8) {L1,L2}; t==1 -> vmcnt(12) {L2,S0,L3};
//   2<=t<6 -> vmcnt(16) {S,L,S,L}; t==6 -> vmcnt(12); t==7 -> vmcnt(8).
// Miscount -> stale frags -> absmax explodes (fail-loud).
//
// Staging swizzle (both-sides-or-neither): LDS dest LINEAR; global source
// chunk permuted (chunk m' of row r holds global chunk m'^(r&7)); ds_read
// applies the same XOR.
// A-frag: lane (g,c): row c, k=8g+i. C/D: col=lane&15, row=4*(lane>>4)+reg.
// h bounce rows PACKED (dword at 4c = (h[c],h[c+16])); W2 frag uses the same
// k-permutation so the MFMA k-reduction is unchanged.

#define N_IN  64
#define N_MID 32
#define N_OUT 10

#define WAVES_PER_BLOCK 4
#define TILES_PER_WAVE  8
#define ROWS_PER_TILE   16
#define ROWS_PER_BLOCK  (WAVES_PER_BLOCK * TILES_PER_WAVE * ROWS_PER_TILE)  // 512
#define NBUF            3
#define H_STRIDE        80        // bytes per h-row in LDS (64 data + 16 pad)
#define XTILE_BYTES     4096      // 16 rows * 256 B
#define ROW_BYTES       256
#define AUX_NT          2         // CPol NT bit (gfx9xx): no-allocate streaming

typedef short bf16x8 __attribute__((ext_vector_type(8)));
typedef float f32x4  __attribute__((ext_vector_type(4)));

typedef __attribute__((address_space(3))) unsigned char       lds_u8_as;
typedef const __attribute__((address_space(1))) unsigned char glb_u8_as;

static __device__ __forceinline__ short f2bf(float f) {
    __bf16 h = (__bf16)f;
    return __builtin_bit_cast(short, h);
}

static __device__ __forceinline__ unsigned pk2bf(float lo, float hi) {
    unsigned l = (unsigned short)__builtin_bit_cast(unsigned short, (__bf16)lo);
    unsigned h = (unsigned short)__builtin_bit_cast(unsigned short, (__bf16)hi);
    return (h << 16) | l;
}

__global__ __launch_bounds__(256)
void livenet_mfma(const float* __restrict__ x,
                  const float* __restrict__ W1,
                  const float* __restrict__ b1,
                  const float* __restrict__ W2,
                  const float* __restrict__ b2,
                  float* __restrict__ out,
                  int batch) {
    __shared__ __align__(16) unsigned char xstage_all[WAVES_PER_BLOCK][NBUF * XTILE_BYTES];
    __shared__ __align__(16) unsigned char h_lds_all[WAVES_PER_BLOCK][ROWS_PER_TILE * H_STRIDE];

    const int lane = threadIdx.x & 63;
    const int wave = threadIdx.x >> 6;
    const int g    = lane >> 4;   // 0..3 : k-group
    const int c    = lane & 15;   // 0..15: row (A) / col (B,C)

    unsigned char* xstage = xstage_all[wave];
    unsigned char* h_lds  = h_lds_all[wave];

    // ---- weight fragments, once per wave ----
    bf16x8 w1f[2][2];  // [n-tile][k-half]
    #pragma unroll
    for (int n = 0; n < 2; ++n)
        #pragma unroll
        for (int p = 0; p < 2; ++p)
            #pragma unroll
            for (int i = 0; i < 8; ++i) {
                int k = p * 32 + 8 * g + i;
                w1f[n][p][i] = f2bf(W1[k * N_MID + n * 16 + c]);
            }

    // W2 fragment in the PACKED-h k-order: position p holds col (p&1)*16+(p>>1).
    bf16x8 w2f;
    #pragma unroll
    for (int i = 0; i < 8; ++i) {
        int kpos = 8 * g + i;
        int col  = (kpos & 1) * 16 + (kpos >> 1);
        w2f[i] = (c < N_OUT) ? f2bf(W2[col * N_OUT + c]) : (short)0;
    }

    const float b1v0 = b1[c];
    const float b1v1 = b1[16 + c];
    const float b2v  = (c < N_OUT) ? b2[c] : 0.0f;

    // ---- per-lane staging source offsets (swizzled global permutation) ----
    const int r_lo    = lane >> 4;
    const int mprime  = lane & 15;
    unsigned srcoff[4];
    #pragma unroll
    for (int j = 0; j < 4; ++j) {
        int r = 4 * j + r_lo;
        srcoff[j] = (unsigned)(r * ROW_BYTES + 16 * (mprime ^ (r & 7)));
    }

    // ---- fragment read offsets (swizzled): row c, chunks {2g,2g+1,8+2g,9+2g} ----
    const int cw = c & 7;
    const unsigned rd_a0lo = (unsigned)(c * ROW_BYTES + 16 * ((2 * g)     ^ cw));
    const unsigned rd_a0hi = (unsigned)(c * ROW_BYTES + 16 * ((2 * g + 1) ^ cw));
    const unsigned rd_a1lo = (unsigned)(c * ROW_BYTES + 16 * ((8 + 2 * g) ^ cw));
    const unsigned rd_a1hi = (unsigned)(c * ROW_BYTES + 16 * ((9 + 2 * g) ^ cw));

    const size_t wave_row0 = (size_t)blockIdx.x * ROWS_PER_BLOCK
                           + (size_t)wave * (TILES_PER_WAVE * ROWS_PER_TILE);
    const bool full = (wave_row0 + TILES_PER_WAVE * ROWS_PER_TILE) <= (size_t)batch;

    if (full) {
        const unsigned char* xb = (const unsigned char*)x + wave_row0 * ROW_BYTES;

        // ---- prologue: stage tile 0 -> buf 0, tile 1 -> buf 1 ----
        #pragma unroll
        for (int j = 0; j < 4; ++j) {
            __builtin_amdgcn_global_load_lds(
                (glb_u8_as*)(xb + srcoff[j]),
                (lds_u8_as*)(xstage + 0 * XTILE_BYTES + j * 1024), 16, 0, AUX_NT);
        }
        #pragma unroll
        for (int j = 0; j < 4; ++j) {
            __builtin_amdgcn_global_load_lds(
                (glb_u8_as*)(xb + XTILE_BYTES + srcoff[j]),
                (lds_u8_as*)(xstage + 1 * XTILE_BYTES + j * 1024), 16, 0, AUX_NT);
        }

        #pragma unroll
        for (int t = 0; t < TILES_PER_WAVE; ++t) {
            // ---- issue stage of tile t+2 into buf (t+2)%3 (before the wait) ----
            if (t + 2 < TILES_PER_WAVE) {
                const unsigned char* src = xb + (size_t)(t + 2) * XTILE_BYTES;
                unsigned char* nbuf = xstage + ((t + 2) % NBUF) * XTILE_BYTES;
                #pragma unroll
                for (int j = 0; j < 4; ++j) {
                    __builtin_amdgcn_global_load_lds(
                        (glb_u8_as*)(src + srcoff[j]),
                        (lds_u8_as*)(nbuf + j * 1024), 16, 0, AUX_NT);
                }
            }

            // ---- counted wait: guarantee tile t's staging is complete ----
            if (t == 0) {
                __asm__ volatile("s_waitcnt vmcnt(8)" ::: "memory");
            } else if (t == 1) {
                __asm__ volatile("s_waitcnt vmcnt(12)" ::: "memory");
            } else if (t == TILES_PER_WAVE - 2) {
                __asm__ volatile("s_waitcnt vmcnt(12)" ::: "memory");
            } else if (t == TILES_PER_WAVE - 1) {
                __asm__ volatile("s_waitcnt vmcnt(8)" ::: "memory");
            } else {
                __asm__ volatile("s_waitcnt vmcnt(16)" ::: "memory");
            }
            __builtin_amdgcn_sched_barrier(0);

            const unsigned char* xbuf = xstage + (t % NBUF) * XTILE_BYTES;

            // ---- fragment reads from staged tile (swizzled, balanced banks) ----
            const float4 f0 = *(const float4*)(xbuf + rd_a0lo);
            const float4 f1 = *(const float4*)(xbuf + rd_a0hi);
            const float4 f2 = *(const float4*)(xbuf + rd_a1lo);
            const float4 f3 = *(const float4*)(xbuf + rd_a1hi);

            // ---- cvt + layer 1 ----
            bf16x8 a0, a1;
            a0[0] = f2bf(f0.x); a0[1] = f2bf(f0.y); a0[2] = f2bf(f0.z); a0[3] = f2bf(f0.w);
            a0[4] = f2bf(f1.x); a0[5] = f2bf(f1.y); a0[6] = f2bf(f1.z); a0[7] = f2bf(f1.w);
            a1[0] = f2bf(f2.x); a1[1] = f2bf(f2.y); a1[2] = f2bf(f2.z); a1[3] = f2bf(f2.w);
            a1[4] = f2bf(f3.x); a1[5] = f2bf(f3.y); a1[6] = f2bf(f3.z); a1[7] = f2bf(f3.w);

            f32x4 acc0 = {b1v0, b1v0, b1v0, b1v0};
            f32x4 acc1 = {b1v1, b1v1, b1v1, b1v1};
            acc0 = __builtin_amdgcn_mfma_f32_16x16x32_bf16(a0, w1f[0][0], acc0, 0, 0, 0);
            acc0 = __builtin_amdgcn_mfma_f32_16x16x32_bf16(a1, w1f[0][1], acc0, 0, 0, 0);
            acc1 = __builtin_amdgcn_mfma_f32_16x16x32_bf16(a0, w1f[1][0], acc1, 0, 0, 0);
            acc1 = __builtin_amdgcn_mfma_f32_16x16x32_bf16(a1, w1f[1][1], acc1, 0, 0, 0);

            // ---- relu + packed transpose write: dword = (h[c], h[c+16]) ----
            #pragma unroll
            for (int r = 0; r < 4; ++r) {
                const int rowr = 4 * g + r;
                *(unsigned*)(h_lds + rowr * H_STRIDE + 4 * c) =
                    pk2bf(fmaxf(acc0[r], 0.0f), fmaxf(acc1[r], 0.0f));
            }
            __asm__ volatile("" ::: "memory");

            // ---- layer 2 ----
            const bf16x8 hfrag = *(const bf16x8*)(h_lds + c * H_STRIDE + 16 * g);
            f32x4 acc2 = {b2v, b2v, b2v, b2v};
            acc2 = __builtin_amdgcn_mfma_f32_16x16x32_bf16(hfrag, w2f, acc2, 0, 0, 0);

            __asm__ volatile("" ::: "memory");

            // ---- store: 4 NT stores per iteration (exec-masked) ----
            if (c < N_OUT) {
                const size_t rb = wave_row0 + (size_t)t * ROWS_PER_TILE;
                float* op = out + (rb + 4 * g) * N_OUT + c;
                __builtin_nontemporal_store(acc2[0], op + 0 * N_OUT);
                __builtin_nontemporal_store(acc2[1], op + 1 * N_OUT);
                __builtin_nontemporal_store(acc2[2], op + 2 * N_OUT);
                __builtin_nontemporal_store(acc2[3], op + 3 * N_OUT);
            }
        }
    } else {
        // ---- tail path (partial blocks; not taken: batch % 512 == 0) ----
        for (int t = 0; t < TILES_PER_WAVE; ++t) {
            const size_t rb = wave_row0 + (size_t)t * ROWS_PER_TILE;
            if (rb + ROWS_PER_TILE > (size_t)batch) break;

            const float* xp = x + (rb + (size_t)c) * N_IN + 8 * g;
            float4 v0 = *(const float4*)(xp + 0);
            float4 v1 = *(const float4*)(xp + 4);
            float4 v2 = *(const float4*)(xp + 32);
            float4 v3 = *(const float4*)(xp + 36);

            bf16x8 a0, a1;
            a0[0] = f2bf(v0.x); a0[1] = f2bf(v0.y); a0[2] = f2bf(v0.z); a0[3] = f2bf(v0.w);
            a0[4] = f2bf(v1.x); a0[5] = f2bf(v1.y); a0[6] = f2bf(v1.z); a0[7] = f2bf(v1.w);
            a1[0] = f2bf(v2.x); a1[1] = f2bf(v2.y); a1[2] = f2bf(v2.z); a1[3] = f2bf(v2.w);
            a1[4] = f2bf(v3.x); a1[5] = f2bf(v3.y); a1[6] = f2bf(v3.z); a1[7] = f2bf(v3.w);

            f32x4 acc0 = {b1v0, b1v0, b1v0, b1v0};
            f32x4 acc1 = {b1v1, b1v1, b1v1, b1v1};
            acc0 = __builtin_amdgcn_mfma_f32_16x16x32_bf16(a0, w1f[0][0], acc0, 0, 0, 0);
            acc0 = __builtin_amdgcn_mfma_f32_16x16x32_bf16(a1, w1f[0][1], acc0, 0, 0, 0);
            acc1 = __builtin_amdgcn_mfma_f32_16x16x32_bf16(a0, w1f[1][0], acc1, 0, 0, 0);
            acc1 = __builtin_amdgcn_mfma_f32_16x16x32_bf16(a1, w1f[1][1], acc1, 0, 0, 0);

            #pragma unroll
            for (int r = 0; r < 4; ++r) {
                const int rowr = 4 * g + r;
                *(unsigned*)(h_lds + rowr * H_STRIDE + 4 * c) =
                    pk2bf(fmaxf(acc0[r], 0.0f), fmaxf(acc1[r], 0.0f));
            }
            __asm__ volatile("" ::: "memory");

            const bf16x8 hfrag = *(const bf16x8*)(h_lds + c * H_STRIDE + 16 * g);
            f32x4 acc2 = {b2v, b2v, b2v, b2v};
            acc2 = __builtin_amdgcn_mfma_f32_16x16x32_bf16(hfrag, w2f, acc2, 0, 0, 0);

            __asm__ volatile("" ::: "memory");

            if (c < N_OUT) {
                float* op = out + (rb + 4 * g) * N_OUT + c;
                op[0 * N_OUT] = acc2[0];
                op[1 * N_OUT] = acc2[1];
                op[2 * N_OUT] = acc2[2];
                op[3 * N_OUT] = acc2[3];
            }
        }
    }
}

extern "C" void kernel_launch(void* const* d_in, const int* in_sizes, int n_in,
                              void* d_out, int out_size, void* d_ws, size_t ws_size,
                              hipStream_t stream) {
    const float* x  = (const float*)d_in[0];
    const float* W1 = (const float*)d_in[1];
    const float* b1 = (const float*)d_in[2];
    const float* W2 = (const float*)d_in[3];
    const float* b2 = (const float*)d_in[4];
    float* out = (float*)d_out;

    int batch = in_sizes[0] / N_IN;                             // 1048576
    int grid  = (batch + ROWS_PER_BLOCK - 1) / ROWS_PER_BLOCK;  // 2048
    livenet_mfma<<<grid, 256, 0, stream>>>(x, W1, b1, W2, b2, out, batch);
}